// Round 4
// baseline (1187.337 us; speedup 1.0000x reference)
//
#include <hip/hip_runtime.h>
#include <hip/hip_bf16.h>

// Problem constants (fixed by the reference: N=50000, E=400000, D=128, H=256, L=5)
#define NNODES 50000
#define MPAD 50048          // 782 * 64 (gemm row padding)
#define NEDGES 400000
#define DIM 128
#define HID 256
#define NLAYERS 5
#define BONDSZ 13
#define BN_EPS 1e-5f
#define NCHUNK 49           // ceil(50000/1024)
#define INVN (1.0f / 50000.0f)

typedef __bf16 bf16x8 __attribute__((ext_vector_type(8)));
typedef float f32x4 __attribute__((ext_vector_type(4)));

// ===========================================================================
// CSR build (once per call — edge topology is layer-invariant)
// ===========================================================================
__global__ __launch_bounds__(256) void hist_kernel(
    const int* __restrict__ dst, int* __restrict__ deg)
{
    int e = blockIdx.x * 256 + threadIdx.x;
    if (e < NEDGES) atomicAdd(&deg[dst[e]], 1);
}

__global__ __launch_bounds__(256) void scan_sum(
    const int* __restrict__ deg, int* __restrict__ partial)
{
    __shared__ int red[256];
    int base = blockIdx.x * 1024;
    int s = 0;
    for (int i = threadIdx.x; i < 1024; i += 256) {
        int idx = base + i;
        if (idx < NNODES) s += deg[idx];
    }
    red[threadIdx.x] = s;
    __syncthreads();
    for (int off = 128; off > 0; off >>= 1) {
        if (threadIdx.x < off) red[threadIdx.x] += red[threadIdx.x + off];
        __syncthreads();
    }
    if (threadIdx.x == 0) partial[blockIdx.x] = red[0];
}

__global__ void scan_part(int* __restrict__ partial, int n, int* __restrict__ rowptr_last)
{
    if (threadIdx.x == 0) {
        int acc = 0;
        for (int i = 0; i < n; i++) { int v = partial[i]; partial[i] = acc; acc += v; }
        rowptr_last[0] = acc;
    }
}

__global__ __launch_bounds__(256) void scan_write(
    const int* __restrict__ deg, const int* __restrict__ partial,
    int* __restrict__ row_ptr)
{
    __shared__ int red[256];
    int base = blockIdx.x * 1024;
    int t = threadIdx.x;
    int v[4];
    int s = 0;
    #pragma unroll
    for (int j = 0; j < 4; j++) {
        int idx = base + t * 4 + j;
        v[j] = (idx < NNODES) ? deg[idx] : 0;
        s += v[j];
    }
    red[t] = s;
    __syncthreads();
    for (int off = 1; off < 256; off <<= 1) {
        int x = (t >= off) ? red[t - off] : 0;
        __syncthreads();
        red[t] += x;
        __syncthreads();
    }
    int ex = red[t] - s + partial[blockIdx.x];
    #pragma unroll
    for (int j = 0; j < 4; j++) {
        int idx = base + t * 4 + j;
        if (idx < NNODES) row_ptr[idx] = ex;
        ex += v[j];
    }
}

__global__ __launch_bounds__(256) void scatter_kernel(
    const int* __restrict__ src, const int* __restrict__ dst,
    const int* __restrict__ eattr, const int* __restrict__ row_ptr,
    int* __restrict__ cursor, int* __restrict__ esrc, int* __restrict__ ebond)
{
    int e = blockIdx.x * 256 + threadIdx.x;
    if (e >= NEDGES) return;
    int d = dst[e];
    int pos = row_ptr[d] + atomicAdd(&cursor[d], 1);
    esrc[pos] = src[e];
    int a0 = eattr[e * 3 + 0];
    int a1 = eattr[e * 3 + 1];
    int a2 = eattr[e * 3 + 2];
    ebond[pos] = a0 | ((5 + a1) << 4) | ((11 + a2) << 8);
}

// ===========================================================================
// Weight pre-split (once): W -> transposed [n][k] bf16 hi/lo planes
// ===========================================================================
__global__ __launch_bounds__(256) void wsplit_kernel(
    const float* __restrict__ W1, const float* __restrict__ W2,
    __bf16* __restrict__ bt1h, __bf16* __restrict__ bt1l,
    __bf16* __restrict__ bt2h, __bf16* __restrict__ bt2l)
{
    int gid = blockIdx.x * 256 + threadIdx.x;
    const int total1 = NLAYERS * DIM * HID;
    if (gid < total1) {
        int n = gid % HID; int k = (gid / HID) % DIM; int l = gid / (DIM * HID);
        float w = W1[gid];
        __bf16 hi = (__bf16)w;
        int o = (l * HID + n) * DIM + k;
        bt1h[o] = hi; bt1l[o] = (__bf16)(w - (float)hi);
    } else {
        int g = gid - total1;
        if (g < NLAYERS * HID * DIM) {
            int n = g % DIM; int k = (g / DIM) % HID; int l = g / (HID * DIM);
            float w = W2[g];
            __bf16 hi = (__bf16)w;
            int o = (l * DIM + n) * HID + k;
            bt2h[o] = hi; bt2l[o] = (__bf16)(w - (float)hi);
        }
    }
}

// ===========================================================================
// Aggregation + GIN combine (CSR, zero atomics), with previous layer's outer
// BN + inter-layer ReLU fused on the gather path (TRANS=1). Writes z as
// pre-split bf16 hi/lo planes for gemm1. Block 0 zeroes this layer's stats.
// One wave per node, float2 per lane, edge loop unrolled x4.
// ===========================================================================
template<int TRANS>
__global__ __launch_bounds__(256) void agg_combine(
    const float* __restrict__ hin,
    const int* __restrict__ row_ptr, const int* __restrict__ esrc,
    const int* __restrict__ ebond, const float* __restrict__ bond,
    const float* __restrict__ epsv, int lidx,
    const float* __restrict__ csIn, const float* __restrict__ cqIn,
    const float* __restrict__ gamma, const float* __restrict__ beta,
    __bf16* __restrict__ zH, __bf16* __restrict__ zL,
    float* __restrict__ statsZero)
{
    __shared__ float T[BONDSZ * DIM];
    __shared__ float scs[DIM], shs[DIM];
    for (int i = threadIdx.x; i < BONDSZ * DIM; i += 256) T[i] = bond[i];
    if (TRANS && threadIdx.x < DIM) {
        int c = threadIdx.x;
        float mu = csIn[c] * INVN;
        float var = cqIn[c] * INVN - mu * mu;
        float sv = gamma[c] * rsqrtf(var + BN_EPS);
        scs[c] = sv; shs[c] = beta[c] - mu * sv;
    }
    if (blockIdx.x == 0)
        for (int i = threadIdx.x; i < 768; i += 256) statsZero[i] = 0.f;
    __syncthreads();

    const int wavei = threadIdx.x >> 6;
    const int lane = threadIdx.x & 63;
    const int node = blockIdx.x * 4 + wavei;
    const int f = lane * 2;
    float s0 = 1.f, s1 = 1.f, t0 = 0.f, t1 = 0.f;
    if (TRANS) { s0 = scs[f]; s1 = scs[f + 1]; t0 = shs[f]; t1 = shs[f + 1]; }

    float accx = 0.f, accy = 0.f;
    const int s = row_ptr[node];
    const int e2 = row_ptr[node + 1];
    int i = s;
    for (; i + 3 < e2; i += 4) {
        int sn0 = esrc[i], sn1 = esrc[i + 1], sn2 = esrc[i + 2], sn3 = esrc[i + 3];
        int pk0 = ebond[i], pk1 = ebond[i + 1], pk2 = ebond[i + 2], pk3 = ebond[i + 3];
        float2 g0 = *(const float2*)&hin[(size_t)sn0 * DIM + f];
        float2 g1 = *(const float2*)&hin[(size_t)sn1 * DIM + f];
        float2 g2 = *(const float2*)&hin[(size_t)sn2 * DIM + f];
        float2 g3 = *(const float2*)&hin[(size_t)sn3 * DIM + f];
        if (TRANS) {
            g0.x = fmaxf(s0 * g0.x + t0, 0.f); g0.y = fmaxf(s1 * g0.y + t1, 0.f);
            g1.x = fmaxf(s0 * g1.x + t0, 0.f); g1.y = fmaxf(s1 * g1.y + t1, 0.f);
            g2.x = fmaxf(s0 * g2.x + t0, 0.f); g2.y = fmaxf(s1 * g2.y + t1, 0.f);
            g3.x = fmaxf(s0 * g3.x + t0, 0.f); g3.y = fmaxf(s1 * g3.y + t1, 0.f);
        }
        {
            float2 a = *(const float2*)&T[(pk0 & 15) * DIM + f];
            float2 b = *(const float2*)&T[((pk0 >> 4) & 15) * DIM + f];
            float2 c = *(const float2*)&T[((pk0 >> 8) & 15) * DIM + f];
            accx += fmaxf(g0.x + a.x + b.x + c.x, 0.f);
            accy += fmaxf(g0.y + a.y + b.y + c.y, 0.f);
        }
        {
            float2 a = *(const float2*)&T[(pk1 & 15) * DIM + f];
            float2 b = *(const float2*)&T[((pk1 >> 4) & 15) * DIM + f];
            float2 c = *(const float2*)&T[((pk1 >> 8) & 15) * DIM + f];
            accx += fmaxf(g1.x + a.x + b.x + c.x, 0.f);
            accy += fmaxf(g1.y + a.y + b.y + c.y, 0.f);
        }
        {
            float2 a = *(const float2*)&T[(pk2 & 15) * DIM + f];
            float2 b = *(const float2*)&T[((pk2 >> 4) & 15) * DIM + f];
            float2 c = *(const float2*)&T[((pk2 >> 8) & 15) * DIM + f];
            accx += fmaxf(g2.x + a.x + b.x + c.x, 0.f);
            accy += fmaxf(g2.y + a.y + b.y + c.y, 0.f);
        }
        {
            float2 a = *(const float2*)&T[(pk3 & 15) * DIM + f];
            float2 b = *(const float2*)&T[((pk3 >> 4) & 15) * DIM + f];
            float2 c = *(const float2*)&T[((pk3 >> 8) & 15) * DIM + f];
            accx += fmaxf(g3.x + a.x + b.x + c.x, 0.f);
            accy += fmaxf(g3.y + a.y + b.y + c.y, 0.f);
        }
    }
    for (; i < e2; i++) {
        int sn = esrc[i];
        int pk = ebond[i];
        float2 g = *(const float2*)&hin[(size_t)sn * DIM + f];
        if (TRANS) { g.x = fmaxf(s0 * g.x + t0, 0.f); g.y = fmaxf(s1 * g.y + t1, 0.f); }
        float2 a = *(const float2*)&T[(pk & 15) * DIM + f];
        float2 b = *(const float2*)&T[((pk >> 4) & 15) * DIM + f];
        float2 c = *(const float2*)&T[((pk >> 8) & 15) * DIM + f];
        accx += fmaxf(g.x + a.x + b.x + c.x, 0.f);
        accy += fmaxf(g.y + a.y + b.y + c.y, 0.f);
    }
    float2 hv = *(const float2*)&hin[(size_t)node * DIM + f];
    if (TRANS) { hv.x = fmaxf(s0 * hv.x + t0, 0.f); hv.y = fmaxf(s1 * hv.y + t1, 0.f); }
    float ep = 1.0f + epsv[lidx];
    float zx = ep * hv.x + accx;
    float zy = ep * hv.y + accy;
    __bf16 hx = (__bf16)zx, hy = (__bf16)zy;
    size_t o = (size_t)node * DIM + f;
    zH[o] = hx; zH[o + 1] = hy;
    zL[o] = (__bf16)(zx - (float)hx); zL[o + 1] = (__bf16)(zy - (float)hy);
}

// ===========================================================================
// LDS-free split-precision MFMA GEMM.
//   C = op(A) @ B + bias, A pre-split bf16 H/L planes [MPAD][K],
//   B pre-split transposed [NCOLS][K] H/L planes (L2-resident).
//   op(A) = TRANSFORM ? resplit(relu(scale*(AH+AL)+shift)) : identity,
//   scale/shift computed inline from producer's column stats (BN fusion).
// Block = 2 waves; wave owns 32 rows x all NCOLS. acc in AGPR/VGPR.
// SPLIT_OUT: write bf16 H/L planes (gemm1) else fp32 (gemm2).
// Fused epilogue: per-column sum/sumsq via LDS atomics + global atomics.
// ===========================================================================
template<int K, int NCOLS, int TRANSFORM, int SPLIT_OUT>
__global__ __launch_bounds__(128) void gemm_mfma(
    const __bf16* __restrict__ AH, const __bf16* __restrict__ AL,
    const __bf16* __restrict__ BTH, const __bf16* __restrict__ BTL,
    const float* __restrict__ bias,
    const float* __restrict__ csIn, const float* __restrict__ cqIn,
    const float* __restrict__ gamma, const float* __restrict__ beta,
    float* __restrict__ outF, __bf16* __restrict__ outH, __bf16* __restrict__ outL,
    float* __restrict__ colsum, float* __restrict__ colsumsq)
{
    constexpr int NJ = NCOLS / 16;
    __shared__ float scs[K], shs[K];
    __shared__ float redS[NCOLS], redQ[NCOLS];

    const int tid = threadIdx.x;
    for (int c = tid; c < NCOLS; c += 128) { redS[c] = 0.f; redQ[c] = 0.f; }
    if (TRANSFORM) {
        for (int c = tid; c < K; c += 128) {
            float mu = csIn[c] * INVN;
            float var = cqIn[c] * INVN - mu * mu;
            float sv = gamma[c] * rsqrtf(var + BN_EPS);
            scs[c] = sv; shs[c] = beta[c] - mu * sv;
        }
    }
    __syncthreads();

    const int lane = tid & 63;
    const int wave = tid >> 6;
    const int rowL = lane & 15;
    const int quad = lane >> 4;
    const int rb = blockIdx.x * 64 + wave * 32;

    f32x4 acc[2][NJ] = {};

    for (int kt = 0; kt < K; kt += 32) {
        const int kb = kt + quad * 8;
        bf16x8 aH[2], aL[2];
        #pragma unroll
        for (int i = 0; i < 2; i++) {
            size_t off = (size_t)(rb + i * 16 + rowL) * K + kb;
            aH[i] = *(const bf16x8*)(AH + off);
            aL[i] = *(const bf16x8*)(AL + off);
        }
        if (TRANSFORM) {
            float4 sv0 = *(const float4*)&scs[kb];
            float4 sv1 = *(const float4*)&scs[kb + 4];
            float4 tv0 = *(const float4*)&shs[kb];
            float4 tv1 = *(const float4*)&shs[kb + 4];
            float sv[8] = {sv0.x, sv0.y, sv0.z, sv0.w, sv1.x, sv1.y, sv1.z, sv1.w};
            float tv[8] = {tv0.x, tv0.y, tv0.z, tv0.w, tv1.x, tv1.y, tv1.z, tv1.w};
            #pragma unroll
            for (int i = 0; i < 2; i++) {
                #pragma unroll
                for (int e = 0; e < 8; e++) {
                    float fv = (float)aH[i][e] + (float)aL[i][e];
                    fv = fmaxf(sv[e] * fv + tv[e], 0.f);
                    __bf16 hi = (__bf16)fv;
                    aH[i][e] = hi;
                    aL[i][e] = (__bf16)(fv - (float)hi);
                }
            }
        }
        #pragma unroll
        for (int j = 0; j < NJ; j++) {
            size_t boff = (size_t)(j * 16 + rowL) * K + kb;
            bf16x8 bH = *(const bf16x8*)(BTH + boff);
            bf16x8 bL = *(const bf16x8*)(BTL + boff);
            #pragma unroll
            for (int i = 0; i < 2; i++) {
                acc[i][j] = __builtin_amdgcn_mfma_f32_16x16x32_bf16(aH[i], bH, acc[i][j], 0, 0, 0);
                acc[i][j] = __builtin_amdgcn_mfma_f32_16x16x32_bf16(aL[i], bH, acc[i][j], 0, 0, 0);
                acc[i][j] = __builtin_amdgcn_mfma_f32_16x16x32_bf16(aH[i], bL, acc[i][j], 0, 0, 0);
            }
        }
    }

    // ---- epilogue: bias, store, per-column stats
    #pragma unroll
    for (int j = 0; j < NJ; j++) {
        const int col = j * 16 + rowL;
        const float bb = bias[col];
        float sj = 0.f, qj = 0.f;
        #pragma unroll
        for (int i = 0; i < 2; i++) {
            const int rbase = rb + i * 16 + quad * 4;
            #pragma unroll
            for (int r = 0; r < 4; r++) {
                const int rr = rbase + r;
                if (rr < NNODES) {
                    float v = acc[i][j][r] + bb;
                    size_t o = (size_t)rr * NCOLS + col;
                    if (SPLIT_OUT) {
                        __bf16 hi = (__bf16)v;
                        outH[o] = hi;
                        outL[o] = (__bf16)(v - (float)hi);
                    } else {
                        outF[o] = v;
                    }
                    sj += v;
                    qj += v * v;
                }
            }
        }
        atomicAdd(&redS[col], sj);
        atomicAdd(&redQ[col], qj);
    }
    __syncthreads();
    for (int c = tid; c < NCOLS; c += 128) {
        atomicAdd(&colsum[c], redS[c]);
        atomicAdd(&colsumsq[c], redQ[c]);
    }
}

// ===========================================================================
// Final outer BN (no relu), scale/shift computed inline from layer-4 stats.
// ===========================================================================
__global__ __launch_bounds__(256) void bn_out(
    const float* __restrict__ y2, const float* __restrict__ csIn,
    const float* __restrict__ cqIn, const float* __restrict__ gamma,
    const float* __restrict__ beta, float* __restrict__ out)
{
    __shared__ float scs[DIM], shs[DIM];
    if (threadIdx.x < DIM) {
        int c = threadIdx.x;
        float mu = csIn[c] * INVN;
        float var = cqIn[c] * INVN - mu * mu;
        float sv = gamma[c] * rsqrtf(var + BN_EPS);
        scs[c] = sv; shs[c] = beta[c] - mu * sv;
    }
    __syncthreads();
    int i = blockIdx.x * 256 + threadIdx.x;
    if (i >= NNODES * 32) return;
    int c = (i & 31) * 4;
    float4 v = *(const float4*)&y2[(size_t)i * 4];
    float4 s = *(const float4*)&scs[c];
    float4 t = *(const float4*)&shs[c];
    v.x = v.x * s.x + t.x;
    v.y = v.y * s.y + t.y;
    v.z = v.z * s.z + t.z;
    v.w = v.w * s.w + t.w;
    *(float4*)&out[(size_t)i * 4] = v;
}

extern "C" void kernel_launch(void* const* d_in, const int* in_sizes, int n_in,
                              void* d_out, int out_size, void* d_ws, size_t ws_size,
                              hipStream_t stream)
{
    const float* x    = (const float*)d_in[0];
    const int*   ei   = (const int*)d_in[1];
    const int*   ea   = (const int*)d_in[2];
    const float* W1   = (const float*)d_in[3];
    const float* b1   = (const float*)d_in[4];
    const float* g1   = (const float*)d_in[5];
    const float* bb1  = (const float*)d_in[6];
    const float* W2   = (const float*)d_in[7];
    const float* b2   = (const float*)d_in[8];
    const float* epsv = (const float*)d_in[9];
    const float* bond = (const float*)d_in[10];
    const float* g2   = (const float*)d_in[11];
    const float* bb2  = (const float*)d_in[12];
    float* out = (float*)d_out;

    const int* src = ei;
    const int* dstp = ei + NEDGES;

    // ---- workspace layout
    float* ws = (float*)d_ws;
    float* y2    = ws;                            // MPAD*DIM fp32
    float* stats = y2 + (size_t)MPAD * DIM;       // 2 sets x 768
    __bf16* zH   = (__bf16*)(stats + 2 * 768);
    __bf16* zL   = zH + (size_t)MPAD * DIM;
    __bf16* y1H  = zL + (size_t)MPAD * DIM;
    __bf16* y1L  = y1H + (size_t)MPAD * HID;
    __bf16* bt1h = y1L + (size_t)MPAD * HID;
    __bf16* bt1l = bt1h + (size_t)NLAYERS * DIM * HID;
    __bf16* bt2h = bt1l + (size_t)NLAYERS * DIM * HID;
    __bf16* bt2l = bt2h + (size_t)NLAYERS * HID * DIM;
    int* iws     = (int*)(bt2l + (size_t)NLAYERS * HID * DIM);
    int* deg     = iws;                  // 50000
    int* cursor  = deg + NNODES;         // 50000
    int* row_ptr = cursor + NNODES;      // 50001
    int* partial = row_ptr + NNODES + 1; // 64
    int* esrc    = partial + 64;         // 400000
    int* ebond   = esrc + NEDGES;        // 400000

    // ---- build CSR (dst-sorted edge list) + split weights, once
    hipMemsetAsync(deg, 0, 2 * NNODES * sizeof(int), stream);
    hist_kernel<<<(NEDGES + 255) / 256, 256, 0, stream>>>(dstp, deg);
    scan_sum<<<NCHUNK, 256, 0, stream>>>(deg, partial);
    scan_part<<<1, 64, 0, stream>>>(partial, NCHUNK, row_ptr + NNODES);
    scan_write<<<NCHUNK, 256, 0, stream>>>(deg, partial, row_ptr);
    scatter_kernel<<<(NEDGES + 255) / 256, 256, 0, stream>>>(
        src, dstp, ea, row_ptr, cursor, esrc, ebond);
    wsplit_kernel<<<(2 * NLAYERS * DIM * HID + 255) / 256, 256, 0, stream>>>(
        W1, W2, bt1h, bt1l, bt2h, bt2l);

    const int gemm_grid = MPAD / 64;   // 782

    for (int l = 0; l < NLAYERS; l++) {
        const int p = l & 1;
        float* cs1 = stats + p * 768;
        float* cq1 = cs1 + HID;
        float* cs2 = cq1 + HID;
        float* cq2 = cs2 + DIM;
        float* statsZ = stats + p * 768;   // whole set, zeroed by agg block 0

        if (l == 0) {
            agg_combine<0><<<NNODES / 4, 256, 0, stream>>>(
                x, row_ptr, esrc, ebond, bond + (size_t)l * BONDSZ * DIM,
                epsv, l, nullptr, nullptr, nullptr, nullptr, zH, zL, statsZ);
        } else {
            const int pp = (l - 1) & 1;
            float* pcs2 = stats + pp * 768 + 2 * HID;
            float* pcq2 = pcs2 + DIM;
            agg_combine<1><<<NNODES / 4, 256, 0, stream>>>(
                y2, row_ptr, esrc, ebond, bond + (size_t)l * BONDSZ * DIM,
                epsv, l, pcs2, pcq2, g2 + (size_t)(l - 1) * DIM,
                bb2 + (size_t)(l - 1) * DIM, zH, zL, statsZ);
        }

        gemm_mfma<DIM, HID, 0, 1><<<gemm_grid, 128, 0, stream>>>(
            zH, zL, bt1h + (size_t)l * HID * DIM, bt1l + (size_t)l * HID * DIM,
            b1 + (size_t)l * HID, nullptr, nullptr, nullptr, nullptr,
            nullptr, y1H, y1L, cs1, cq1);

        gemm_mfma<HID, DIM, 1, 0><<<gemm_grid, 128, 0, stream>>>(
            y1H, y1L, bt2h + (size_t)l * DIM * HID, bt2l + (size_t)l * DIM * HID,
            b2 + (size_t)l * DIM, cs1, cq1, g1 + (size_t)l * HID,
            bb1 + (size_t)l * HID, y2, nullptr, nullptr, cs2, cq2);
    }

    // final outer BN (layer 4 -> parity 0), no relu
    {
        float* cs2 = stats + 0 * 768 + 2 * HID;
        float* cq2 = cs2 + DIM;
        bn_out<<<(NNODES * 32 + 255) / 256, 256, 0, stream>>>(
            y2, cs2, cq2, g2 + (size_t)4 * DIM, bb2 + (size_t)4 * DIM, out);
    }
}

// Round 5
// 881.794 us; speedup vs baseline: 1.3465x; 1.3465x over previous
//
#include <hip/hip_runtime.h>
#include <hip/hip_bf16.h>

// Problem constants (fixed by the reference: N=50000, E=400000, D=128, H=256, L=5)
#define NNODES 50000
#define MPAD 50048          // 782 * 64 (gemm row padding)
#define NEDGES 400000
#define DIM 128
#define HID 256
#define NLAYERS 5
#define BONDSZ 13
#define BN_EPS 1e-5f
#define NCHUNK 49           // ceil(50000/1024)
#define INVN (1.0f / 50000.0f)

typedef __bf16 bf16x8 __attribute__((ext_vector_type(8)));
typedef float f32x4 __attribute__((ext_vector_type(4)));

typedef const __attribute__((address_space(1))) void gas_void;
typedef __attribute__((address_space(3))) void las_void;
#define GLLDS16(g, l) __builtin_amdgcn_global_load_lds((gas_void*)(g), (las_void*)(l), 16, 0, 0)

// ===========================================================================
// CSR build (once per call — edge topology is layer-invariant)
// ===========================================================================
__global__ __launch_bounds__(256) void hist_kernel(
    const int* __restrict__ dst, int* __restrict__ deg)
{
    int e = blockIdx.x * 256 + threadIdx.x;
    if (e < NEDGES) atomicAdd(&deg[dst[e]], 1);
}

__global__ __launch_bounds__(256) void scan_sum(
    const int* __restrict__ deg, int* __restrict__ partial)
{
    __shared__ int red[256];
    int base = blockIdx.x * 1024;
    int s = 0;
    for (int i = threadIdx.x; i < 1024; i += 256) {
        int idx = base + i;
        if (idx < NNODES) s += deg[idx];
    }
    red[threadIdx.x] = s;
    __syncthreads();
    for (int off = 128; off > 0; off >>= 1) {
        if (threadIdx.x < off) red[threadIdx.x] += red[threadIdx.x + off];
        __syncthreads();
    }
    if (threadIdx.x == 0) partial[blockIdx.x] = red[0];
}

__global__ void scan_part(int* __restrict__ partial, int n, int* __restrict__ rowptr_last)
{
    if (threadIdx.x == 0) {
        int acc = 0;
        for (int i = 0; i < n; i++) { int v = partial[i]; partial[i] = acc; acc += v; }
        rowptr_last[0] = acc;
    }
}

__global__ __launch_bounds__(256) void scan_write(
    const int* __restrict__ deg, const int* __restrict__ partial,
    int* __restrict__ row_ptr)
{
    __shared__ int red[256];
    int base = blockIdx.x * 1024;
    int t = threadIdx.x;
    int v[4];
    int s = 0;
    #pragma unroll
    for (int j = 0; j < 4; j++) {
        int idx = base + t * 4 + j;
        v[j] = (idx < NNODES) ? deg[idx] : 0;
        s += v[j];
    }
    red[t] = s;
    __syncthreads();
    for (int off = 1; off < 256; off <<= 1) {
        int x = (t >= off) ? red[t - off] : 0;
        __syncthreads();
        red[t] += x;
        __syncthreads();
    }
    int ex = red[t] - s + partial[blockIdx.x];
    #pragma unroll
    for (int j = 0; j < 4; j++) {
        int idx = base + t * 4 + j;
        if (idx < NNODES) row_ptr[idx] = ex;
        ex += v[j];
    }
}

__global__ __launch_bounds__(256) void scatter_kernel(
    const int* __restrict__ src, const int* __restrict__ dst,
    const int* __restrict__ eattr, const int* __restrict__ row_ptr,
    int* __restrict__ cursor, int* __restrict__ esrc, int* __restrict__ ebond)
{
    int e = blockIdx.x * 256 + threadIdx.x;
    if (e >= NEDGES) return;
    int d = dst[e];
    int pos = row_ptr[d] + atomicAdd(&cursor[d], 1);
    esrc[pos] = src[e];
    int a0 = eattr[e * 3 + 0];
    int a1 = eattr[e * 3 + 1];
    int a2 = eattr[e * 3 + 2];
    ebond[pos] = a0 | ((5 + a1) << 4) | ((11 + a2) << 8);
}

// ===========================================================================
// Weight pre-split (once): W -> transposed [n][k] bf16 hi/lo planes
// ===========================================================================
__global__ __launch_bounds__(256) void wsplit_kernel(
    const float* __restrict__ W1, const float* __restrict__ W2,
    __bf16* __restrict__ bt1h, __bf16* __restrict__ bt1l,
    __bf16* __restrict__ bt2h, __bf16* __restrict__ bt2l)
{
    int gid = blockIdx.x * 256 + threadIdx.x;
    const int total1 = NLAYERS * DIM * HID;
    if (gid < total1) {
        int n = gid % HID; int k = (gid / HID) % DIM; int l = gid / (DIM * HID);
        float w = W1[gid];
        __bf16 hi = (__bf16)w;
        int o = (l * HID + n) * DIM + k;
        bt1h[o] = hi; bt1l[o] = (__bf16)(w - (float)hi);
    } else {
        int g = gid - total1;
        if (g < NLAYERS * HID * DIM) {
            int n = g % DIM; int k = (g / DIM) % HID; int l = g / (HID * DIM);
            float w = W2[g];
            __bf16 hi = (__bf16)w;
            int o = (l * DIM + n) * HID + k;
            bt2h[o] = hi; bt2l[o] = (__bf16)(w - (float)hi);
        }
    }
}

// ===========================================================================
// Aggregation + GIN combine (CSR, zero atomics), with previous layer's outer
// BN + inter-layer ReLU fused on the gather path (TRANS=1). Writes z as
// pre-split bf16 hi/lo planes for gemm1. Block 0 zeroes this layer's stats.
// One wave per node, float2 per lane, edge loop unrolled x4.
// ===========================================================================
template<int TRANS>
__global__ __launch_bounds__(256) void agg_combine(
    const float* __restrict__ hin,
    const int* __restrict__ row_ptr, const int* __restrict__ esrc,
    const int* __restrict__ ebond, const float* __restrict__ bond,
    const float* __restrict__ epsv, int lidx,
    const float* __restrict__ csIn, const float* __restrict__ cqIn,
    const float* __restrict__ gamma, const float* __restrict__ beta,
    __bf16* __restrict__ zH, __bf16* __restrict__ zL,
    float* __restrict__ statsZero)
{
    __shared__ float T[BONDSZ * DIM];
    __shared__ float scs[DIM], shs[DIM];
    for (int i = threadIdx.x; i < BONDSZ * DIM; i += 256) T[i] = bond[i];
    if (TRANS && threadIdx.x < DIM) {
        int c = threadIdx.x;
        float mu = csIn[c] * INVN;
        float var = cqIn[c] * INVN - mu * mu;
        float sv = gamma[c] * rsqrtf(var + BN_EPS);
        scs[c] = sv; shs[c] = beta[c] - mu * sv;
    }
    if (blockIdx.x == 0)
        for (int i = threadIdx.x; i < 768; i += 256) statsZero[i] = 0.f;
    __syncthreads();

    const int wavei = threadIdx.x >> 6;
    const int lane = threadIdx.x & 63;
    const int node = blockIdx.x * 4 + wavei;
    const int f = lane * 2;
    float s0 = 1.f, s1 = 1.f, t0 = 0.f, t1 = 0.f;
    if (TRANS) { s0 = scs[f]; s1 = scs[f + 1]; t0 = shs[f]; t1 = shs[f + 1]; }

    float accx = 0.f, accy = 0.f;
    const int s = row_ptr[node];
    const int e2 = row_ptr[node + 1];
    int i = s;
    for (; i + 3 < e2; i += 4) {
        int sn0 = esrc[i], sn1 = esrc[i + 1], sn2 = esrc[i + 2], sn3 = esrc[i + 3];
        int pk0 = ebond[i], pk1 = ebond[i + 1], pk2 = ebond[i + 2], pk3 = ebond[i + 3];
        float2 g0 = *(const float2*)&hin[(size_t)sn0 * DIM + f];
        float2 g1 = *(const float2*)&hin[(size_t)sn1 * DIM + f];
        float2 g2 = *(const float2*)&hin[(size_t)sn2 * DIM + f];
        float2 g3 = *(const float2*)&hin[(size_t)sn3 * DIM + f];
        if (TRANS) {
            g0.x = fmaxf(s0 * g0.x + t0, 0.f); g0.y = fmaxf(s1 * g0.y + t1, 0.f);
            g1.x = fmaxf(s0 * g1.x + t0, 0.f); g1.y = fmaxf(s1 * g1.y + t1, 0.f);
            g2.x = fmaxf(s0 * g2.x + t0, 0.f); g2.y = fmaxf(s1 * g2.y + t1, 0.f);
            g3.x = fmaxf(s0 * g3.x + t0, 0.f); g3.y = fmaxf(s1 * g3.y + t1, 0.f);
        }
        {
            float2 a = *(const float2*)&T[(pk0 & 15) * DIM + f];
            float2 b = *(const float2*)&T[((pk0 >> 4) & 15) * DIM + f];
            float2 c = *(const float2*)&T[((pk0 >> 8) & 15) * DIM + f];
            accx += fmaxf(g0.x + a.x + b.x + c.x, 0.f);
            accy += fmaxf(g0.y + a.y + b.y + c.y, 0.f);
        }
        {
            float2 a = *(const float2*)&T[(pk1 & 15) * DIM + f];
            float2 b = *(const float2*)&T[((pk1 >> 4) & 15) * DIM + f];
            float2 c = *(const float2*)&T[((pk1 >> 8) & 15) * DIM + f];
            accx += fmaxf(g1.x + a.x + b.x + c.x, 0.f);
            accy += fmaxf(g1.y + a.y + b.y + c.y, 0.f);
        }
        {
            float2 a = *(const float2*)&T[(pk2 & 15) * DIM + f];
            float2 b = *(const float2*)&T[((pk2 >> 4) & 15) * DIM + f];
            float2 c = *(const float2*)&T[((pk2 >> 8) & 15) * DIM + f];
            accx += fmaxf(g2.x + a.x + b.x + c.x, 0.f);
            accy += fmaxf(g2.y + a.y + b.y + c.y, 0.f);
        }
        {
            float2 a = *(const float2*)&T[(pk3 & 15) * DIM + f];
            float2 b = *(const float2*)&T[((pk3 >> 4) & 15) * DIM + f];
            float2 c = *(const float2*)&T[((pk3 >> 8) & 15) * DIM + f];
            accx += fmaxf(g3.x + a.x + b.x + c.x, 0.f);
            accy += fmaxf(g3.y + a.y + b.y + c.y, 0.f);
        }
    }
    for (; i < e2; i++) {
        int sn = esrc[i];
        int pk = ebond[i];
        float2 g = *(const float2*)&hin[(size_t)sn * DIM + f];
        if (TRANS) { g.x = fmaxf(s0 * g.x + t0, 0.f); g.y = fmaxf(s1 * g.y + t1, 0.f); }
        float2 a = *(const float2*)&T[(pk & 15) * DIM + f];
        float2 b = *(const float2*)&T[((pk >> 4) & 15) * DIM + f];
        float2 c = *(const float2*)&T[((pk >> 8) & 15) * DIM + f];
        accx += fmaxf(g.x + a.x + b.x + c.x, 0.f);
        accy += fmaxf(g.y + a.y + b.y + c.y, 0.f);
    }
    float2 hv = *(const float2*)&hin[(size_t)node * DIM + f];
    if (TRANS) { hv.x = fmaxf(s0 * hv.x + t0, 0.f); hv.y = fmaxf(s1 * hv.y + t1, 0.f); }
    float ep = 1.0f + epsv[lidx];
    float zx = ep * hv.x + accx;
    float zy = ep * hv.y + accy;
    __bf16 hx = (__bf16)zx, hy = (__bf16)zy;
    size_t o = (size_t)node * DIM + f;
    zH[o] = hx; zH[o + 1] = hy;
    zL[o] = (__bf16)(zx - (float)hx); zL[o + 1] = (__bf16)(zy - (float)hy);
}

// ===========================================================================
// LDS-staged split-precision MFMA GEMM (m97 structure).
//   C = op(A) @ B + bias. A = pre-split bf16 H/L planes [MPAD][K] (no
//   conversion in staging — pure global_load_lds width=16 copies).
//   B = pre-split transposed [NCOLS][K] H/L planes.
//   op(A) = TRANSFORM ? resplit(relu(scale*(AH+AL)+shift)) : identity,
//   scale/shift computed inline from producer's column stats (BN fusion).
// Block: 256 threads / 4 waves (2x2), tile BM x 128, BK=32.
// LDS layout per plane: chunk c = row*4 + (k/8), 16B chunks — lane-order
// contiguous (global_load_lds requirement), m97-style 64B rows.
// SPLIT_OUT: write bf16 H/L planes (gemm1) else fp32 (gemm2).
// Fused epilogue: per-column sum/sumsq via LDS atomics + global atomics.
// ===========================================================================
template<int K, int NCOLS, int BM, int TRANSFORM, int SPLIT_OUT>
__global__ __launch_bounds__(256) void gemm_mfma(
    const __bf16* __restrict__ AH, const __bf16* __restrict__ AL,
    const __bf16* __restrict__ BTH, const __bf16* __restrict__ BTL,
    const float* __restrict__ bias,
    const float* __restrict__ csIn, const float* __restrict__ cqIn,
    const float* __restrict__ gamma, const float* __restrict__ beta,
    float* __restrict__ outF, __bf16* __restrict__ outH, __bf16* __restrict__ outL,
    float* __restrict__ colsum, float* __restrict__ colsumsq)
{
    constexpr int BN = 128;
    constexpr int WM = BM / 2;        // wave tile rows (2x2 wave grid)
    constexpr int NI = WM / 16;
    constexpr int NJ = 4;             // 64 cols per wave
    constexpr int nIA = (BM * 4) / 256;   // 16B chunks per plane / 256 lanes
    constexpr int nIB = (BN * 4) / 256;

    __shared__ __bf16 sAH[BM * 32], sAL[BM * 32];
    __shared__ __bf16 sBH[BN * 32], sBL[BN * 32];
    __shared__ float redS[BN], redQ[BN];
    __shared__ float scs[TRANSFORM ? K : 1], shs[TRANSFORM ? K : 1];

    const int tid = threadIdx.x;
    const int lane = tid & 63;
    const int wv = tid >> 6;
    const int rowL = lane & 15;
    const int quad = lane >> 4;
    const int wave_m = (wv >> 1) * WM;
    const int wave_n = (wv & 1) * 64;
    const int m0 = blockIdx.y * BM;
    const int n0 = blockIdx.x * BN;

    if (tid < BN) { redS[tid] = 0.f; redQ[tid] = 0.f; }
    if (TRANSFORM) {
        for (int c = tid; c < K; c += 256) {
            float mu = csIn[c] * INVN;
            float var = cqIn[c] * INVN - mu * mu;
            float sv = gamma[c] * rsqrtf(var + BN_EPS);
            scs[c] = sv; shs[c] = beta[c] - mu * sv;
        }
    }

    f32x4 acc[NI][NJ] = {};

    for (int kt = 0; kt < K; kt += 32) {
        // ---- async stage A/B H+L planes into LDS (pure copies, 16B/lane)
        #pragma unroll
        for (int t = 0; t < nIA; t++) {
            int c = (wv * nIA + t) * 64 + lane;       // chunk id
            int row = c >> 2, kq = c & 3;
            size_t g = (size_t)(m0 + row) * K + kt + kq * 8;
            GLLDS16(AH + g, sAH + (size_t)c * 8);
            GLLDS16(AL + g, sAL + (size_t)c * 8);
        }
        #pragma unroll
        for (int t = 0; t < nIB; t++) {
            int c = (wv * nIB + t) * 64 + lane;
            int row = c >> 2, kq = c & 3;
            size_t g = (size_t)(n0 + row) * K + kt + kq * 8;
            GLLDS16(BTH + g, sBH + (size_t)c * 8);
            GLLDS16(BTL + g, sBL + (size_t)c * 8);
        }
        __syncthreads();

        bf16x8 aH[NI], aL[NI];
        #pragma unroll
        for (int i = 0; i < NI; i++) {
            int ch = (wave_m + i * 16 + rowL) * 4 + quad;
            aH[i] = *(const bf16x8*)(sAH + ch * 8);
            aL[i] = *(const bf16x8*)(sAL + ch * 8);
        }
        if (TRANSFORM) {
            float sv[8], tv[8];
            #pragma unroll
            for (int e = 0; e < 8; e++) {
                sv[e] = scs[kt + quad * 8 + e];
                tv[e] = shs[kt + quad * 8 + e];
            }
            #pragma unroll
            for (int i = 0; i < NI; i++) {
                #pragma unroll
                for (int e = 0; e < 8; e++) {
                    float fv = (float)aH[i][e] + (float)aL[i][e];
                    fv = fmaxf(sv[e] * fv + tv[e], 0.f);
                    __bf16 hi = (__bf16)fv;
                    aH[i][e] = hi;
                    aL[i][e] = (__bf16)(fv - (float)hi);
                }
            }
        }
        #pragma unroll
        for (int j = 0; j < NJ; j++) {
            int ch = (wave_n + j * 16 + rowL) * 4 + quad;
            bf16x8 bH = *(const bf16x8*)(sBH + ch * 8);
            bf16x8 bL = *(const bf16x8*)(sBL + ch * 8);
            #pragma unroll
            for (int i = 0; i < NI; i++) {
                acc[i][j] = __builtin_amdgcn_mfma_f32_16x16x32_bf16(aH[i], bH, acc[i][j], 0, 0, 0);
                acc[i][j] = __builtin_amdgcn_mfma_f32_16x16x32_bf16(aL[i], bH, acc[i][j], 0, 0, 0);
                acc[i][j] = __builtin_amdgcn_mfma_f32_16x16x32_bf16(aH[i], bL, acc[i][j], 0, 0, 0);
            }
        }
        __syncthreads();
    }

    // ---- epilogue: bias, store, per-column stats
    #pragma unroll
    for (int j = 0; j < NJ; j++) {
        const int col = wave_n + j * 16 + rowL;       // within block tile
        const float bb = bias[n0 + col];
        float sj = 0.f, qj = 0.f;
        #pragma unroll
        for (int i = 0; i < NI; i++) {
            const int rbase = m0 + wave_m + i * 16 + quad * 4;
            #pragma unroll
            for (int r = 0; r < 4; r++) {
                const int rr = rbase + r;
                if (rr < NNODES) {
                    float v = acc[i][j][r] + bb;
                    size_t o = (size_t)rr * NCOLS + n0 + col;
                    if (SPLIT_OUT) {
                        __bf16 hi = (__bf16)v;
                        outH[o] = hi;
                        outL[o] = (__bf16)(v - (float)hi);
                    } else {
                        outF[o] = v;
                    }
                    sj += v;
                    qj += v * v;
                }
            }
        }
        atomicAdd(&redS[col], sj);
        atomicAdd(&redQ[col], qj);
    }
    __syncthreads();
    if (tid < BN) {
        atomicAdd(&colsum[n0 + tid], redS[tid]);
        atomicAdd(&colsumsq[n0 + tid], redQ[tid]);
    }
}

// ===========================================================================
// Final outer BN (no relu), scale/shift computed inline from layer-4 stats.
// ===========================================================================
__global__ __launch_bounds__(256) void bn_out(
    const float* __restrict__ y2, const float* __restrict__ csIn,
    const float* __restrict__ cqIn, const float* __restrict__ gamma,
    const float* __restrict__ beta, float* __restrict__ out)
{
    __shared__ float scs[DIM], shs[DIM];
    if (threadIdx.x < DIM) {
        int c = threadIdx.x;
        float mu = csIn[c] * INVN;
        float var = cqIn[c] * INVN - mu * mu;
        float sv = gamma[c] * rsqrtf(var + BN_EPS);
        scs[c] = sv; shs[c] = beta[c] - mu * sv;
    }
    __syncthreads();
    int i = blockIdx.x * 256 + threadIdx.x;
    if (i >= NNODES * 32) return;
    int c = (i & 31) * 4;
    float4 v = *(const float4*)&y2[(size_t)i * 4];
    float4 s = *(const float4*)&scs[c];
    float4 t = *(const float4*)&shs[c];
    v.x = v.x * s.x + t.x;
    v.y = v.y * s.y + t.y;
    v.z = v.z * s.z + t.z;
    v.w = v.w * s.w + t.w;
    *(float4*)&out[(size_t)i * 4] = v;
}

extern "C" void kernel_launch(void* const* d_in, const int* in_sizes, int n_in,
                              void* d_out, int out_size, void* d_ws, size_t ws_size,
                              hipStream_t stream)
{
    const float* x    = (const float*)d_in[0];
    const int*   ei   = (const int*)d_in[1];
    const int*   ea   = (const int*)d_in[2];
    const float* W1   = (const float*)d_in[3];
    const float* b1   = (const float*)d_in[4];
    const float* g1   = (const float*)d_in[5];
    const float* bb1  = (const float*)d_in[6];
    const float* W2   = (const float*)d_in[7];
    const float* b2   = (const float*)d_in[8];
    const float* epsv = (const float*)d_in[9];
    const float* bond = (const float*)d_in[10];
    const float* g2   = (const float*)d_in[11];
    const float* bb2  = (const float*)d_in[12];
    float* out = (float*)d_out;

    const int* src = ei;
    const int* dstp = ei + NEDGES;

    // ---- workspace layout
    float* ws = (float*)d_ws;
    float* y2    = ws;                            // MPAD*DIM fp32
    float* stats = y2 + (size_t)MPAD * DIM;       // 2 sets x 768
    __bf16* zH   = (__bf16*)(stats + 2 * 768);
    __bf16* zL   = zH + (size_t)MPAD * DIM;
    __bf16* y1H  = zL + (size_t)MPAD * DIM;
    __bf16* y1L  = y1H + (size_t)MPAD * HID;
    __bf16* bt1h = y1L + (size_t)MPAD * HID;
    __bf16* bt1l = bt1h + (size_t)NLAYERS * DIM * HID;
    __bf16* bt2h = bt1l + (size_t)NLAYERS * DIM * HID;
    __bf16* bt2l = bt2h + (size_t)NLAYERS * HID * DIM;
    int* iws     = (int*)(bt2l + (size_t)NLAYERS * HID * DIM);
    int* deg     = iws;                  // 50000
    int* cursor  = deg + NNODES;         // 50000
    int* row_ptr = cursor + NNODES;      // 50001
    int* partial = row_ptr + NNODES + 1; // 64
    int* esrc    = partial + 64;         // 400000
    int* ebond   = esrc + NEDGES;        // 400000

    // ---- build CSR (dst-sorted edge list) + split weights, once
    hipMemsetAsync(deg, 0, 2 * NNODES * sizeof(int), stream);
    hist_kernel<<<(NEDGES + 255) / 256, 256, 0, stream>>>(dstp, deg);
    scan_sum<<<NCHUNK, 256, 0, stream>>>(deg, partial);
    scan_part<<<1, 64, 0, stream>>>(partial, NCHUNK, row_ptr + NNODES);
    scan_write<<<NCHUNK, 256, 0, stream>>>(deg, partial, row_ptr);
    scatter_kernel<<<(NEDGES + 255) / 256, 256, 0, stream>>>(
        src, dstp, ea, row_ptr, cursor, esrc, ebond);
    wsplit_kernel<<<(2 * NLAYERS * DIM * HID + 255) / 256, 256, 0, stream>>>(
        W1, W2, bt1h, bt1l, bt2h, bt2l);

    for (int l = 0; l < NLAYERS; l++) {
        const int p = l & 1;
        float* cs1 = stats + p * 768;
        float* cq1 = cs1 + HID;
        float* cs2 = cq1 + HID;
        float* cq2 = cs2 + DIM;
        float* statsZ = stats + p * 768;   // whole set, zeroed by agg block 0

        if (l == 0) {
            agg_combine<0><<<NNODES / 4, 256, 0, stream>>>(
                x, row_ptr, esrc, ebond, bond + (size_t)l * BONDSZ * DIM,
                epsv, l, nullptr, nullptr, nullptr, nullptr, zH, zL, statsZ);
        } else {
            const int pp = (l - 1) & 1;
            float* pcs2 = stats + pp * 768 + 2 * HID;
            float* pcq2 = pcs2 + DIM;
            agg_combine<1><<<NNODES / 4, 256, 0, stream>>>(
                y2, row_ptr, esrc, ebond, bond + (size_t)l * BONDSZ * DIM,
                epsv, l, pcs2, pcq2, g2 + (size_t)(l - 1) * DIM,
                bb2 + (size_t)(l - 1) * DIM, zH, zL, statsZ);
        }

        // gemm1: [MPAD x 128] @ [128 x 256], tile 128x128, grid (2, 391)
        gemm_mfma<DIM, HID, 128, 0, 1><<<dim3(HID / 128, MPAD / 128), 256, 0, stream>>>(
            zH, zL, bt1h + (size_t)l * HID * DIM, bt1l + (size_t)l * HID * DIM,
            b1 + (size_t)l * HID, nullptr, nullptr, nullptr, nullptr,
            nullptr, y1H, y1L, cs1, cq1);

        // gemm2: [MPAD x 256] @ [256 x 128], tile 64x128, grid (1, 782)
        gemm_mfma<HID, DIM, 64, 1, 0><<<dim3(DIM / 128, MPAD / 64), 256, 0, stream>>>(
            y1H, y1L, bt2h + (size_t)l * DIM * HID, bt2l + (size_t)l * DIM * HID,
            b2 + (size_t)l * DIM, cs1, cq1, g1 + (size_t)l * HID,
            bb1 + (size_t)l * HID, y2, nullptr, nullptr, cs2, cq2);
    }

    // final outer BN (layer 4 -> parity 0), no relu
    {
        float* cs2 = stats + 0 * 768 + 2 * HID;
        float* cq2 = cs2 + DIM;
        bn_out<<<(NNODES * 32 + 255) / 256, 256, 0, stream>>>(
            y2, cs2, cq2, g2 + (size_t)4 * DIM, bb2 + (size_t)4 * DIM, out);
    }
}

// Round 6
// 830.181 us; speedup vs baseline: 1.4302x; 1.0622x over previous
//
#include <hip/hip_runtime.h>
#include <hip/hip_bf16.h>

// Problem constants (fixed by the reference: N=50000, E=400000, D=128, H=256, L=5)
#define NNODES 50000
#define MPAD 50048          // 391 * 128 (gemm row padding)
#define NEDGES 400000
#define DIM 128
#define HID 256
#define NLAYERS 5
#define BONDSZ 13
#define BN_EPS 1e-5f
#define NCHUNK 49           // ceil(50000/1024)
#define INVN (1.0f / 50000.0f)

typedef __bf16 bf16x8 __attribute__((ext_vector_type(8)));
typedef float f32x4 __attribute__((ext_vector_type(4)));

// ===========================================================================
// CSR build (once per call — edge topology is layer-invariant)
// ===========================================================================
__global__ __launch_bounds__(256) void hist_kernel(
    const int* __restrict__ dst, int* __restrict__ deg)
{
    int e = blockIdx.x * 256 + threadIdx.x;
    if (e < NEDGES) atomicAdd(&deg[dst[e]], 1);
}

__global__ __launch_bounds__(256) void scan_sum(
    const int* __restrict__ deg, int* __restrict__ partial)
{
    __shared__ int red[256];
    int base = blockIdx.x * 1024;
    int s = 0;
    for (int i = threadIdx.x; i < 1024; i += 256) {
        int idx = base + i;
        if (idx < NNODES) s += deg[idx];
    }
    red[threadIdx.x] = s;
    __syncthreads();
    for (int off = 128; off > 0; off >>= 1) {
        if (threadIdx.x < off) red[threadIdx.x] += red[threadIdx.x + off];
        __syncthreads();
    }
    if (threadIdx.x == 0) partial[blockIdx.x] = red[0];
}

__global__ void scan_part(int* __restrict__ partial, int n, int* __restrict__ rowptr_last)
{
    if (threadIdx.x == 0) {
        int acc = 0;
        for (int i = 0; i < n; i++) { int v = partial[i]; partial[i] = acc; acc += v; }
        rowptr_last[0] = acc;
    }
}

__global__ __launch_bounds__(256) void scan_write(
    const int* __restrict__ deg, const int* __restrict__ partial,
    int* __restrict__ row_ptr)
{
    __shared__ int red[256];
    int base = blockIdx.x * 1024;
    int t = threadIdx.x;
    int v[4];
    int s = 0;
    #pragma unroll
    for (int j = 0; j < 4; j++) {
        int idx = base + t * 4 + j;
        v[j] = (idx < NNODES) ? deg[idx] : 0;
        s += v[j];
    }
    red[t] = s;
    __syncthreads();
    for (int off = 1; off < 256; off <<= 1) {
        int x = (t >= off) ? red[t - off] : 0;
        __syncthreads();
        red[t] += x;
        __syncthreads();
    }
    int ex = red[t] - s + partial[blockIdx.x];
    #pragma unroll
    for (int j = 0; j < 4; j++) {
        int idx = base + t * 4 + j;
        if (idx < NNODES) row_ptr[idx] = ex;
        ex += v[j];
    }
}

__global__ __launch_bounds__(256) void scatter_kernel(
    const int* __restrict__ src, const int* __restrict__ dst,
    const int* __restrict__ eattr, const int* __restrict__ row_ptr,
    int* __restrict__ cursor, int* __restrict__ esrc, int* __restrict__ ebond)
{
    int e = blockIdx.x * 256 + threadIdx.x;
    if (e >= NEDGES) return;
    int d = dst[e];
    int pos = row_ptr[d] + atomicAdd(&cursor[d], 1);
    esrc[pos] = src[e];
    int a0 = eattr[e * 3 + 0];
    int a1 = eattr[e * 3 + 1];
    int a2 = eattr[e * 3 + 2];
    ebond[pos] = a0 | ((5 + a1) << 4) | ((11 + a2) << 8);
}

// ===========================================================================
// Weight pre-split (once): W -> transposed [n][k] bf16 hi/lo planes
// ===========================================================================
__global__ __launch_bounds__(256) void wsplit_kernel(
    const float* __restrict__ W1, const float* __restrict__ W2,
    __bf16* __restrict__ bt1h, __bf16* __restrict__ bt1l,
    __bf16* __restrict__ bt2h, __bf16* __restrict__ bt2l)
{
    int gid = blockIdx.x * 256 + threadIdx.x;
    const int total1 = NLAYERS * DIM * HID;
    if (gid < total1) {
        int n = gid % HID; int k = (gid / HID) % DIM; int l = gid / (DIM * HID);
        float w = W1[gid];
        __bf16 hi = (__bf16)w;
        int o = (l * HID + n) * DIM + k;
        bt1h[o] = hi; bt1l[o] = (__bf16)(w - (float)hi);
    } else {
        int g = gid - total1;
        if (g < NLAYERS * HID * DIM) {
            int n = g % DIM; int k = (g / DIM) % HID; int l = g / (HID * DIM);
            float w = W2[g];
            __bf16 hi = (__bf16)w;
            int o = (l * DIM + n) * HID + k;
            bt2h[o] = hi; bt2l[o] = (__bf16)(w - (float)hi);
        }
    }
}

// ===========================================================================
// Aggregation + GIN combine (CSR, zero atomics), with previous layer's outer
// BN + inter-layer ReLU fused on the gather path (TRANS=1). Writes z as
// pre-split bf16 hi/lo planes for gemm1. Block 0 zeroes this layer's stats.
// One wave per node, float2 per lane, edge loop unrolled x4.
// ===========================================================================
template<int TRANS>
__global__ __launch_bounds__(256) void agg_combine(
    const float* __restrict__ hin,
    const int* __restrict__ row_ptr, const int* __restrict__ esrc,
    const int* __restrict__ ebond, const float* __restrict__ bond,
    const float* __restrict__ epsv, int lidx,
    const float* __restrict__ csIn, const float* __restrict__ cqIn,
    const float* __restrict__ gamma, const float* __restrict__ beta,
    __bf16* __restrict__ zH, __bf16* __restrict__ zL,
    float* __restrict__ statsZero)
{
    __shared__ float T[BONDSZ * DIM];
    __shared__ float scs[DIM], shs[DIM];
    for (int i = threadIdx.x; i < BONDSZ * DIM; i += 256) T[i] = bond[i];
    if (TRANS && threadIdx.x < DIM) {
        int c = threadIdx.x;
        float mu = csIn[c] * INVN;
        float var = cqIn[c] * INVN - mu * mu;
        float sv = gamma[c] * rsqrtf(var + BN_EPS);
        scs[c] = sv; shs[c] = beta[c] - mu * sv;
    }
    if (blockIdx.x == 0)
        for (int i = threadIdx.x; i < 768; i += 256) statsZero[i] = 0.f;
    __syncthreads();

    const int wavei = threadIdx.x >> 6;
    const int lane = threadIdx.x & 63;
    const int node = blockIdx.x * 4 + wavei;
    const int f = lane * 2;
    float s0 = 1.f, s1 = 1.f, t0 = 0.f, t1 = 0.f;
    if (TRANS) { s0 = scs[f]; s1 = scs[f + 1]; t0 = shs[f]; t1 = shs[f + 1]; }

    float accx = 0.f, accy = 0.f;
    const int s = row_ptr[node];
    const int e2 = row_ptr[node + 1];
    int i = s;
    for (; i + 3 < e2; i += 4) {
        int sn0 = esrc[i], sn1 = esrc[i + 1], sn2 = esrc[i + 2], sn3 = esrc[i + 3];
        int pk0 = ebond[i], pk1 = ebond[i + 1], pk2 = ebond[i + 2], pk3 = ebond[i + 3];
        float2 g0 = *(const float2*)&hin[(size_t)sn0 * DIM + f];
        float2 g1 = *(const float2*)&hin[(size_t)sn1 * DIM + f];
        float2 g2 = *(const float2*)&hin[(size_t)sn2 * DIM + f];
        float2 g3 = *(const float2*)&hin[(size_t)sn3 * DIM + f];
        if (TRANS) {
            g0.x = fmaxf(s0 * g0.x + t0, 0.f); g0.y = fmaxf(s1 * g0.y + t1, 0.f);
            g1.x = fmaxf(s0 * g1.x + t0, 0.f); g1.y = fmaxf(s1 * g1.y + t1, 0.f);
            g2.x = fmaxf(s0 * g2.x + t0, 0.f); g2.y = fmaxf(s1 * g2.y + t1, 0.f);
            g3.x = fmaxf(s0 * g3.x + t0, 0.f); g3.y = fmaxf(s1 * g3.y + t1, 0.f);
        }
        {
            float2 a = *(const float2*)&T[(pk0 & 15) * DIM + f];
            float2 b = *(const float2*)&T[((pk0 >> 4) & 15) * DIM + f];
            float2 c = *(const float2*)&T[((pk0 >> 8) & 15) * DIM + f];
            accx += fmaxf(g0.x + a.x + b.x + c.x, 0.f);
            accy += fmaxf(g0.y + a.y + b.y + c.y, 0.f);
        }
        {
            float2 a = *(const float2*)&T[(pk1 & 15) * DIM + f];
            float2 b = *(const float2*)&T[((pk1 >> 4) & 15) * DIM + f];
            float2 c = *(const float2*)&T[((pk1 >> 8) & 15) * DIM + f];
            accx += fmaxf(g1.x + a.x + b.x + c.x, 0.f);
            accy += fmaxf(g1.y + a.y + b.y + c.y, 0.f);
        }
        {
            float2 a = *(const float2*)&T[(pk2 & 15) * DIM + f];
            float2 b = *(const float2*)&T[((pk2 >> 4) & 15) * DIM + f];
            float2 c = *(const float2*)&T[((pk2 >> 8) & 15) * DIM + f];
            accx += fmaxf(g2.x + a.x + b.x + c.x, 0.f);
            accy += fmaxf(g2.y + a.y + b.y + c.y, 0.f);
        }
        {
            float2 a = *(const float2*)&T[(pk3 & 15) * DIM + f];
            float2 b = *(const float2*)&T[((pk3 >> 4) & 15) * DIM + f];
            float2 c = *(const float2*)&T[((pk3 >> 8) & 15) * DIM + f];
            accx += fmaxf(g3.x + a.x + b.x + c.x, 0.f);
            accy += fmaxf(g3.y + a.y + b.y + c.y, 0.f);
        }
    }
    for (; i < e2; i++) {
        int sn = esrc[i];
        int pk = ebond[i];
        float2 g = *(const float2*)&hin[(size_t)sn * DIM + f];
        if (TRANS) { g.x = fmaxf(s0 * g.x + t0, 0.f); g.y = fmaxf(s1 * g.y + t1, 0.f); }
        float2 a = *(const float2*)&T[(pk & 15) * DIM + f];
        float2 b = *(const float2*)&T[((pk >> 4) & 15) * DIM + f];
        float2 c = *(const float2*)&T[((pk >> 8) & 15) * DIM + f];
        accx += fmaxf(g.x + a.x + b.x + c.x, 0.f);
        accy += fmaxf(g.y + a.y + b.y + c.y, 0.f);
    }
    float2 hv = *(const float2*)&hin[(size_t)node * DIM + f];
    if (TRANS) { hv.x = fmaxf(s0 * hv.x + t0, 0.f); hv.y = fmaxf(s1 * hv.y + t1, 0.f); }
    float ep = 1.0f + epsv[lidx];
    float zx = ep * hv.x + accx;
    float zy = ep * hv.y + accy;
    __bf16 hx = (__bf16)zx, hy = (__bf16)zy;
    size_t o = (size_t)node * DIM + f;
    zH[o] = hx; zH[o + 1] = hy;
    zL[o] = (__bf16)(zx - (float)hx); zL[o + 1] = (__bf16)(zy - (float)hy);
}

// ===========================================================================
// Barrier-free-K-loop split-precision MFMA GEMM ("persistent B").
//   The whole B panel for a 64-col slice (transposed [col][k] bf16 H/L) is
//   staged in LDS ONCE (swizzled: chunk slot kq^(col&15) -> ~2-way banks,
//   which is free), then the K-loop has NO barriers: A fragments are loaded
//   directly from global in MFMA layout (4 loads/kstep — compiler pipelines),
//   B fragments from LDS.
//   TRANSFORM=1: A is fp32; BN(scale/shift from producer stats)+ReLU+split
//   applied in-register on the A path. Else A is pre-split bf16 H/L planes.
//   Output fp32 + fused per-column sum/sumsq (LDS reduce + 1 global atomic).
// Block: 256 thr / 4 waves stacked vertically = 128 rows x 64 cols.
// ===========================================================================
template<int K, int NCOLS, int TRANSFORM>
__global__ __launch_bounds__(256) void gemm_pb(
    const __bf16* __restrict__ AH, const __bf16* __restrict__ AL,
    const float* __restrict__ AF,
    const __bf16* __restrict__ BTH, const __bf16* __restrict__ BTL,
    const float* __restrict__ bias,
    const float* __restrict__ csIn, const float* __restrict__ cqIn,
    const float* __restrict__ gamma, const float* __restrict__ beta,
    float* __restrict__ outF,
    float* __restrict__ colsum, float* __restrict__ colsumsq)
{
    constexpr int KC = K / 8;      // 16B chunks per col
    constexpr int NK = K / 32;     // ksteps

    __shared__ __bf16 sBH[64 * K], sBL[64 * K];
    __shared__ float redS[64], redQ[64];
    __shared__ float scs[TRANSFORM ? K : 1], shs[TRANSFORM ? K : 1];

    const int tid = threadIdx.x;
    const int lane = tid & 63;
    const int wv = tid >> 6;
    const int rowL = lane & 15;
    const int quad = lane >> 4;
    const int n0 = blockIdx.x * 64;
    const int r0 = blockIdx.y * 128 + wv * 32;

    // ---- stage B panel once (swizzled chunk layout)
    #pragma unroll
    for (int it = 0; it < (64 * KC) / 256; it++) {
        int c = it * 256 + tid;
        int col = c / KC, kq = c % KC;
        int slot = col * KC + (kq ^ (col & 15));
        size_t g = (size_t)(n0 + col) * K + kq * 8;
        bf16x8 vh = *(const bf16x8*)(BTH + g);
        bf16x8 vl = *(const bf16x8*)(BTL + g);
        *(bf16x8*)(sBH + slot * 8) = vh;
        *(bf16x8*)(sBL + slot * 8) = vl;
    }
    if (tid < 64) { redS[tid] = 0.f; redQ[tid] = 0.f; }
    if (TRANSFORM) {
        for (int c = tid; c < K; c += 256) {
            float mu = csIn[c] * INVN;
            float var = cqIn[c] * INVN - mu * mu;
            float sv = gamma[c] * rsqrtf(var + BN_EPS);
            scs[c] = sv; shs[c] = beta[c] - mu * sv;
        }
    }
    __syncthreads();   // the only barrier before the epilogue

    f32x4 acc[2][4] = {};

    #pragma unroll
    for (int kt = 0; kt < NK; kt++) {
        const int kb = kt * 32 + quad * 8;
        bf16x8 aH[2], aL[2];
        #pragma unroll
        for (int i = 0; i < 2; i++) {
            size_t off = (size_t)(r0 + i * 16 + rowL) * K + kb;
            if (!TRANSFORM) {
                aH[i] = *(const bf16x8*)(AH + off);
                aL[i] = *(const bf16x8*)(AL + off);
            } else {
                float4 f0 = *(const float4*)(AF + off);
                float4 f1 = *(const float4*)(AF + off + 4);
                float4 sv0 = *(const float4*)&scs[kb];
                float4 sv1 = *(const float4*)&scs[kb + 4];
                float4 tv0 = *(const float4*)&shs[kb];
                float4 tv1 = *(const float4*)&shs[kb + 4];
                float fv[8] = {f0.x, f0.y, f0.z, f0.w, f1.x, f1.y, f1.z, f1.w};
                float sv[8] = {sv0.x, sv0.y, sv0.z, sv0.w, sv1.x, sv1.y, sv1.z, sv1.w};
                float tv[8] = {tv0.x, tv0.y, tv0.z, tv0.w, tv1.x, tv1.y, tv1.z, tv1.w};
                #pragma unroll
                for (int e = 0; e < 8; e++) {
                    float v = fmaxf(fv[e] * sv[e] + tv[e], 0.f);
                    __bf16 hi = (__bf16)v;
                    aH[i][e] = hi;
                    aL[i][e] = (__bf16)(v - (float)hi);
                }
            }
        }
        const int kqr = kt * 4 + quad;
        #pragma unroll
        for (int j = 0; j < 4; j++) {
            int col = j * 16 + rowL;
            int slot = col * KC + (kqr ^ rowL);
            bf16x8 bH = *(const bf16x8*)(sBH + slot * 8);
            bf16x8 bL = *(const bf16x8*)(sBL + slot * 8);
            #pragma unroll
            for (int i = 0; i < 2; i++) {
                acc[i][j] = __builtin_amdgcn_mfma_f32_16x16x32_bf16(aH[i], bH, acc[i][j], 0, 0, 0);
                acc[i][j] = __builtin_amdgcn_mfma_f32_16x16x32_bf16(aL[i], bH, acc[i][j], 0, 0, 0);
                acc[i][j] = __builtin_amdgcn_mfma_f32_16x16x32_bf16(aH[i], bL, acc[i][j], 0, 0, 0);
            }
        }
    }

    // ---- epilogue: bias, fp32 store, per-column stats
    #pragma unroll
    for (int j = 0; j < 4; j++) {
        const int colL = j * 16 + rowL;
        const float bb = bias[n0 + colL];
        float sj = 0.f, qj = 0.f;
        #pragma unroll
        for (int i = 0; i < 2; i++) {
            const int rbase = r0 + i * 16 + quad * 4;
            #pragma unroll
            for (int r = 0; r < 4; r++) {
                const int rr = rbase + r;
                if (rr < NNODES) {
                    float v = acc[i][j][r] + bb;
                    outF[(size_t)rr * NCOLS + n0 + colL] = v;
                    sj += v;
                    qj += v * v;
                }
            }
        }
        atomicAdd(&redS[colL], sj);
        atomicAdd(&redQ[colL], qj);
    }
    __syncthreads();
    if (tid < 64) {
        atomicAdd(&colsum[n0 + tid], redS[tid]);
        atomicAdd(&colsumsq[n0 + tid], redQ[tid]);
    }
}

// ===========================================================================
// Final outer BN (no relu), scale/shift computed inline from layer-4 stats.
// ===========================================================================
__global__ __launch_bounds__(256) void bn_out(
    const float* __restrict__ y2, const float* __restrict__ csIn,
    const float* __restrict__ cqIn, const float* __restrict__ gamma,
    const float* __restrict__ beta, float* __restrict__ out)
{
    __shared__ float scs[DIM], shs[DIM];
    if (threadIdx.x < DIM) {
        int c = threadIdx.x;
        float mu = csIn[c] * INVN;
        float var = cqIn[c] * INVN - mu * mu;
        float sv = gamma[c] * rsqrtf(var + BN_EPS);
        scs[c] = sv; shs[c] = beta[c] - mu * sv;
    }
    __syncthreads();
    int i = blockIdx.x * 256 + threadIdx.x;
    if (i >= NNODES * 32) return;
    int c = (i & 31) * 4;
    float4 v = *(const float4*)&y2[(size_t)i * 4];
    float4 s = *(const float4*)&scs[c];
    float4 t = *(const float4*)&shs[c];
    v.x = v.x * s.x + t.x;
    v.y = v.y * s.y + t.y;
    v.z = v.z * s.z + t.z;
    v.w = v.w * s.w + t.w;
    *(float4*)&out[(size_t)i * 4] = v;
}

extern "C" void kernel_launch(void* const* d_in, const int* in_sizes, int n_in,
                              void* d_out, int out_size, void* d_ws, size_t ws_size,
                              hipStream_t stream)
{
    const float* x    = (const float*)d_in[0];
    const int*   ei   = (const int*)d_in[1];
    const int*   ea   = (const int*)d_in[2];
    const float* W1   = (const float*)d_in[3];
    const float* b1   = (const float*)d_in[4];
    const float* g1   = (const float*)d_in[5];
    const float* bb1  = (const float*)d_in[6];
    const float* W2   = (const float*)d_in[7];
    const float* b2   = (const float*)d_in[8];
    const float* epsv = (const float*)d_in[9];
    const float* bond = (const float*)d_in[10];
    const float* g2   = (const float*)d_in[11];
    const float* bb2  = (const float*)d_in[12];
    float* out = (float*)d_out;

    const int* src = ei;
    const int* dstp = ei + NEDGES;

    // ---- workspace layout
    float* ws = (float*)d_ws;
    float* y2    = ws;                            // MPAD*DIM fp32
    float* y1F   = y2 + (size_t)MPAD * DIM;       // MPAD*HID fp32
    float* stats = y1F + (size_t)MPAD * HID;      // 2 sets x 768
    __bf16* zH   = (__bf16*)(stats + 2 * 768);
    __bf16* zL   = zH + (size_t)MPAD * DIM;
    __bf16* bt1h = zL + (size_t)MPAD * DIM;
    __bf16* bt1l = bt1h + (size_t)NLAYERS * DIM * HID;
    __bf16* bt2h = bt1l + (size_t)NLAYERS * DIM * HID;
    __bf16* bt2l = bt2h + (size_t)NLAYERS * HID * DIM;
    int* iws     = (int*)(bt2l + (size_t)NLAYERS * HID * DIM);
    int* deg     = iws;                  // 50000
    int* cursor  = deg + NNODES;         // 50000
    int* row_ptr = cursor + NNODES;      // 50001
    int* partial = row_ptr + NNODES + 1; // 64
    int* esrc    = partial + 64;         // 400000
    int* ebond   = esrc + NEDGES;        // 400000

    // ---- build CSR (dst-sorted edge list) + split weights, once
    hipMemsetAsync(deg, 0, 2 * NNODES * sizeof(int), stream);
    hist_kernel<<<(NEDGES + 255) / 256, 256, 0, stream>>>(dstp, deg);
    scan_sum<<<NCHUNK, 256, 0, stream>>>(deg, partial);
    scan_part<<<1, 64, 0, stream>>>(partial, NCHUNK, row_ptr + NNODES);
    scan_write<<<NCHUNK, 256, 0, stream>>>(deg, partial, row_ptr);
    scatter_kernel<<<(NEDGES + 255) / 256, 256, 0, stream>>>(
        src, dstp, ea, row_ptr, cursor, esrc, ebond);
    wsplit_kernel<<<(2 * NLAYERS * DIM * HID + 255) / 256, 256, 0, stream>>>(
        W1, W2, bt1h, bt1l, bt2h, bt2l);

    for (int l = 0; l < NLAYERS; l++) {
        const int p = l & 1;
        float* cs1 = stats + p * 768;
        float* cq1 = cs1 + HID;
        float* cs2 = cq1 + HID;
        float* cq2 = cs2 + DIM;
        float* statsZ = stats + p * 768;   // whole set, zeroed by agg block 0

        if (l == 0) {
            agg_combine<0><<<NNODES / 4, 256, 0, stream>>>(
                x, row_ptr, esrc, ebond, bond + (size_t)l * BONDSZ * DIM,
                epsv, l, nullptr, nullptr, nullptr, nullptr, zH, zL, statsZ);
        } else {
            const int pp = (l - 1) & 1;
            float* pcs2 = stats + pp * 768 + 2 * HID;
            float* pcq2 = pcs2 + DIM;
            agg_combine<1><<<NNODES / 4, 256, 0, stream>>>(
                y2, row_ptr, esrc, ebond, bond + (size_t)l * BONDSZ * DIM,
                epsv, l, pcs2, pcq2, g2 + (size_t)(l - 1) * DIM,
                bb2 + (size_t)(l - 1) * DIM, zH, zL, statsZ);
        }

        // gemm1: [MPAD x 128] @ [128 x 256] -> y1F, grid (4, 391), 32KB LDS
        gemm_pb<DIM, HID, 0><<<dim3(HID / 64, MPAD / 128), 256, 0, stream>>>(
            zH, zL, nullptr,
            bt1h + (size_t)l * HID * DIM, bt1l + (size_t)l * HID * DIM,
            b1 + (size_t)l * HID, nullptr, nullptr, nullptr, nullptr,
            y1F, cs1, cq1);

        // gemm2: [MPAD x 256] @ [256 x 128] -> y2, grid (2, 391), 64KB LDS
        gemm_pb<HID, DIM, 1><<<dim3(DIM / 64, MPAD / 128), 256, 0, stream>>>(
            nullptr, nullptr, y1F,
            bt2h + (size_t)l * DIM * HID, bt2l + (size_t)l * DIM * HID,
            b2 + (size_t)l * DIM, cs1, cq1, g1 + (size_t)l * HID,
            bb1 + (size_t)l * HID, y2, cs2, cq2);
    }

    // final outer BN (layer 4 -> parity 0), no relu
    {
        float* cs2 = stats + 0 * 768 + 2 * HID;
        float* cq2 = cs2 + DIM;
        bn_out<<<(NNODES * 32 + 255) / 256, 256, 0, stream>>>(
            y2, cs2, cq2, g2 + (size_t)4 * DIM, bb2 + (size_t)4 * DIM, out);
    }
}